// Round 3
// baseline (197.308 us; speedup 1.0000x reference)
//
#include <hip/hip_runtime.h>

// FD_discretizer on fixed 1024x1024 grid, Ex=Ey=1026 extended grid.
// Round 3: interior fast path (straight-line contiguous loads, 2 outputs per
// thread) + slow path (analytic ghost-BC gather) for boundary outputs only.
// One block per grid row: 512 threads x 2 outputs = 1024 columns.

#define NXC 1024               // NX == NY
#define EXC 1026               // Ex == Ey
#define NN  (NXC*NXC)

enum { T_NORMAL=0, T_INFLOW=4, T_OUTFLOW=5, T_WALL=6, T_PRESS=7 };

struct V3 { float u,v,p; };

__device__ __forceinline__ int ntype(int io,int jo){
  if (io==NXC-1) return T_OUTFLOW;
  if (io==0)     return T_INFLOW;
  if (jo==0 || jo==NXC-1) return T_WALL;
  return T_NORMAL;
}

// BC-enforced extended field value at extended coords (je,ie) in [0,1025]^2.
// NEWF: apply PRESS_POINT p=0 at (513,513) (only for the "new" field).
template<bool NEWF>
__device__ __forceinline__ V3 ext_at(int je,int ie,
    const float* __restrict__ uvp,
    const float* __restrict__ node_y)
{
  V3 r;
  const bool bl=(ie==0), br=(ie==EXC-1), bb=(je==0), bt=(je==EXC-1);
  const bool onx = bl||br, ony = bb||bt;
  const bool ghost = (onx && !ony) || (ony && !onx);   // ring minus corners
  if (!ghost){
    int io = ie-1; io = io<0?0:(io>NXC-1?NXC-1:io);
    int jo = je-1; jo = jo<0?0:(jo>NXC-1?NXC-1:jo);
    int m3 = 3*(jo*NXC+io);
    r.u = uvp[m3]; r.v = uvp[m3+1]; r.p = uvp[m3+2];
    if (NEWF && je==EXC/2 && ie==EXC/2) r.p = 0.f;     // PRESS_POINT
    return r;
  }
  int dje=0, die=0, gt;
  if (bl)      { die= 1; gt=T_INFLOW;  }
  else if (br) { die=-1; gt=T_OUTFLOW; }
  else if (bb) { dje= 1; gt=T_WALL;    }
  else         { dje=-1; gt=T_WALL;    }
  int io1 = ie+die-1, jo1 = je+dje-1;
  int m1 = 3*(jo1*NXC+io1);
  int m2 = 3*((jo1+dje)*NXC + (io1+die));
  float u2=uvp[m2], v2=uvp[m2+1], p2=uvp[m2+2];
  int nt1 = ntype(io1,jo1);
  if (gt==T_OUTFLOW){
    float p1 = (nt1==T_OUTFLOW) ? 0.f : uvp[m1+2];
    r.u=u2; r.v=v2; r.p = 2.f*p1 - p2;
  } else {
    float du,dv;
    if (nt1==T_INFLOW || nt1==T_WALL){ du=node_y[m1]; dv=node_y[m1+1]; }
    else                             { du=uvp[m1];    dv=uvp[m1+1];    }
    r.u = 2.f*du - u2; r.v = 2.f*dv - v2; r.p = p2;
  }
  return r;
}

// full slow-path computation for one output node (round-2-verified)
__device__ void process_slow(int io,int jo,
    const float* __restrict__ uvp, const float* __restrict__ uvo,
    const float* __restrict__ ndy, const float* __restrict__ ebm,
    float dt,float uc,float cc,float convc,float pc,float dc,float relax,
    float* __restrict__ out)
{
  const int o = jo*NXC + io;
  const int ie0 = io+1, je0 = jo+1;
  V3 C  = ext_at<true >(je0,  ie0,  uvp, ndy);
  V3 W  = ext_at<true >(je0,  ie0-1,uvp, ndy);
  V3 E  = ext_at<true >(je0,  ie0+1,uvp, ndy);
  V3 S  = ext_at<true >(je0-1,ie0,  uvp, ndy);
  V3 Nn = ext_at<true >(je0+1,ie0,  uvp, ndy);
  V3 SW = ext_at<true >(je0-1,ie0-1,uvp, ndy);
  V3 SE = ext_at<true >(je0-1,ie0+1,uvp, ndy);
  V3 NW = ext_at<true >(je0+1,ie0-1,uvp, ndy);
  V3 NE = ext_at<true >(je0+1,ie0+1,uvp, ndy);
  V3 Co = ext_at<false>(je0,  ie0,  uvo, ndy);
  V3 Wo = ext_at<false>(je0,  ie0-1,uvo, ndy);
  V3 Eo = ext_at<false>(je0,  ie0+1,uvo, ndy);
  V3 So = ext_at<false>(je0-1,ie0,  uvo, ndy);
  V3 No = ext_at<false>(je0+1,ie0,  uvo, ndy);

  const int eC = je0*EXC+ie0;
  const int eW = eC-1, eE = eC+1, eS = eC-EXC, eN = eC+EXC;
  float dxxC=ebm[5*eC+0], dxyC=ebm[5*eC+1], dexC=ebm[5*eC+2],
        deyC=ebm[5*eC+3], JmC=ebm[5*eC+4];
  float dxxW=ebm[5*eW+0], dxyW=ebm[5*eW+1], JmW=ebm[5*eW+4];
  float dxxE=ebm[5*eE+0], dxyE=ebm[5*eE+1], JmE=ebm[5*eE+4];
  float dexS=ebm[5*eS+2], deyS=ebm[5*eS+3], JmS=ebm[5*eS+4];
  float dexN=ebm[5*eN+2], deyN=ebm[5*eN+3], JmN=ebm[5*eN+4];
  const float rC=1.f/JmC, rW=1.f/JmW, rE=1.f/JmE, rS=1.f/JmS, rN=1.f/JmN;

  float UC=(C.u*dxxC + C.v*dxyC)*rC, UW=(W.u*dxxW + W.v*dxyW)*rW, UE=(E.u*dxxE + E.v*dxyE)*rE;
  float VC=(C.u*dexC + C.v*deyC)*rC, VS=(S.u*dexS + S.v*deyS)*rS, VN=(Nn.u*dexN + Nn.v*deyN)*rN;
  float UCo=(Co.u*dxxC + Co.v*dxyC)*rC, UWo=(Wo.u*dxxW + Wo.v*dxyW)*rW, UEo=(Eo.u*dxxE + Eo.v*dxyE)*rE;
  float VCo=(Co.u*dexC + Co.v*deyC)*rC, VSo=(So.u*dexS + So.v*deyS)*rS, VNo=(No.u*dexN + No.v*deyN)*rN;

  float Ufl =0.5f*(UW +UC ), Ufr =0.5f*(UC +UE );
  float Vfd =0.5f*(VS +VC ), Vfu =0.5f*(VC +VN );
  float Uflo=0.5f*(UWo+UCo), Ufro=0.5f*(UCo+UEo);
  float Vfdo=0.5f*(VSo+VCo), Vfuo=0.5f*(VCo+VNo);

  const float loss = (Ufr - Ufl + Vfu - Vfd) * cc;

  float cnu = 0.5f*(C.u+E.u)*Ufr - 0.5f*(W.u+C.u)*Ufl + 0.5f*(C.u+Nn.u)*Vfu - 0.5f*(S.u+C.u)*Vfd;
  float cnv = 0.5f*(C.v+E.v)*Ufr - 0.5f*(W.v+C.v)*Ufl + 0.5f*(C.v+Nn.v)*Vfu - 0.5f*(S.v+C.v)*Vfd;
  float cou = 0.5f*(Co.u+Eo.u)*Ufro - 0.5f*(Wo.u+Co.u)*Uflo + 0.5f*(Co.u+No.u)*Vfuo - 0.5f*(So.u+Co.u)*Vfdo;
  float cov = 0.5f*(Co.v+Eo.v)*Ufro - 0.5f*(Wo.v+Co.v)*Uflo + 0.5f*(Co.v+No.v)*Vfuo - 0.5f*(So.v+Co.v)*Vfdo;
  const float convu = relax*cou + (1.f-relax)*cnu;
  const float convv = relax*cov + (1.f-relax)*cnv;

  float a11C=(dxxC*dxxC+dxyC*dxyC)*rC, a11W=(dxxW*dxxW+dxyW*dxyW)*rW, a11E=(dxxE*dxxE+dxyE*dxyE)*rE;
  float a22C=(dexC*dexC+deyC*deyC)*rC, a22S=(dexS*dexS+deyS*deyS)*rS, a22N=(dexN*dexN+deyN*deyN)*rN;
  float du = 0.5f*(a11C+a11E)*(E.u -C.u) - 0.5f*(a11W+a11C)*(C.u-W.u)
           + 0.5f*(a22C+a22N)*(Nn.u-C.u) - 0.5f*(a22S+a22C)*(C.u-S.u);
  float dv = 0.5f*(a11C+a11E)*(E.v -C.v) - 0.5f*(a11W+a11C)*(C.v-W.v)
           + 0.5f*(a22C+a22N)*(Nn.v-C.v) - 0.5f*(a22S+a22C)*(C.v-S.v);

  float pqW=W.p*rW, pqE=E.p*rE, pqS=S.p*rS, pqN=Nn.p*rN;
  const float gPx = 0.5f*(pqE*dxxE - pqW*dxxW) + 0.5f*(pqN*dexN - pqS*dexS);
  const float gPy = 0.5f*(pqN*deyN - pqS*deyS) + 0.5f*(pqE*dxyE - pqW*dxyW);

  const float rdt = 1.f/dt;
  const float unst_u = (C.u - Co.u)*rdt*rC;
  const float unst_v = (C.v - Co.v)*rdt*rC;

  const float momu = uc*unst_u + convc*convu + pc*gPx - dc*du;
  const float momv = uc*unst_v + convc*convv + pc*gPy - dc*dv;

  const float visu = (SW.u+SE.u+NW.u+NE.u + 2.f*(S.u+W.u+E.u+Nn.u) + 4.f*C.u)*0.0625f;
  const float visv = (SW.v+SE.v+NW.v+NE.v + 2.f*(S.v+W.v+E.v+Nn.v) + 4.f*C.v)*0.0625f;
  const float visp = (SW.p+SE.p+NW.p+NE.p + 2.f*(S.p+W.p+E.p+Nn.p) + 4.f*C.p)*0.0625f;

  out[o]        = loss;
  out[NN + o]   = momu;
  out[2*NN + o] = momv;
  const int vb = 3*NN + 3*o;
  out[vb]   = visu;
  out[vb+1] = visv;
  out[vb+2] = visp;
}

extern "C" __global__ void __launch_bounds__(512)
fd_kernel(const float* __restrict__ uvp,     // original_uv  n x 3
          const float* __restrict__ uvo,     // uv_old       n x 3
          const float* __restrict__ ndy,     // node_y       n x 3
          const float* __restrict__ ebm,     // ext metrics  n_ext x 5
          const float* __restrict__ dtg,     // dt           1
          const float* __restrict__ th,      // pde_theta    5
          const float* __restrict__ rl,      // relaxation   1
          float* __restrict__ out)
{
  const int jo = blockIdx.x;                 // one block per grid row
  int t = threadIdx.x;
  // swizzle: put both x-edge strips (0 and 511) into wave 0
  int s = (t==63) ? 511 : ((t==511) ? 63 : t);
  const int x0 = s*2;                        // this thread's 2 output columns

  // scalars (uniform -> scalar loads)
  const float dt   = dtg[0];
  const float uc   = th[0], cc = th[1], convc = th[2], pc = th[3], dc = th[4];
  const float relax= rl[0];
  const float rdt  = 1.f/dt;

  const bool edge = (x0==0) | (x0==NXC-2) | (jo==0) | (jo==NXC-1);
  if (edge){
    process_slow(x0,  jo, uvp,uvo,ndy,ebm, dt,uc,cc,convc,pc,dc,relax, out);
    process_slow(x0+1,jo, uvp,uvo,ndy,ebm, dt,uc,cc,convc,pc,dc,relax, out);
    return;
  }

  // ---------------- fast path: fully interior 2-wide strip ----------------
  // patch cols c=0..3 <-> interior cols x0-1+c <-> ext cols x0+c
  const int rm=jo-1, rc=jo, rp=jo+1;

  float nS[12], nC[12], nN[12];              // new field, 3 rows x 4 nodes x (u,v,p)
  {
    const float* a = uvp + 3*(rm*NXC + x0-1);
    const float* b = uvp + 3*(rc*NXC + x0-1);
    const float* c = uvp + 3*(rp*NXC + x0-1);
    #pragma unroll
    for (int k=0;k<12;k++){ nS[k]=a[k]; nC[k]=b[k]; nN[k]=c[k]; }
  }
  float qS[6], qC[12], qN[6];                // old field
  {
    const float* a = uvo + 3*(rm*NXC + x0);
    const float* b = uvo + 3*(rc*NXC + x0-1);
    const float* c = uvo + 3*(rp*NXC + x0);
    #pragma unroll
    for (int k=0;k<6;k++){ qS[k]=a[k]; qN[k]=c[k]; }
    #pragma unroll
    for (int k=0;k<12;k++){ qC[k]=b[k]; }
  }
  float mc[20], ms[10], mn[10];              // metrics: center 4 nodes, N/S 2 nodes
  {
    const float* a = ebm + 5*((jo  )*EXC + x0+1);
    const float* b = ebm + 5*((jo+1)*EXC + x0);
    const float* c = ebm + 5*((jo+2)*EXC + x0+1);
    #pragma unroll
    for (int k=0;k<10;k++){ ms[k]=a[k]; mn[k]=c[k]; }
    #pragma unroll
    for (int k=0;k<20;k++){ mc[k]=b[k]; }
  }

  // PRESS_POINT: interior node (512,512) p=0 in the NEW field only
  {
    const int c = 513 - x0;                  // patch col of interior col 512
    if ((unsigned)c < 4u){
      if (rm==512) nS[3*c+2]=0.f;
      if (rc==512) nC[3*c+2]=0.f;
      if (rp==512) nN[3*c+2]=0.f;
    }
  }

  // center-row per-column quantities
  float Un[4],Uo[4],a11[4],pqx[4],pqy[4],rJ[4],dex_[4],dey_[4];
  #pragma unroll
  for (int k=0;k<4;k++){
    const float dxx=mc[5*k], dxy=mc[5*k+1];
    dex_[k]=mc[5*k+2]; dey_[k]=mc[5*k+3];
    rJ[k]=1.f/mc[5*k+4];
    Un[k]=(nC[3*k]*dxx + nC[3*k+1]*dxy)*rJ[k];
    Uo[k]=(qC[3*k]*dxx + qC[3*k+1]*dxy)*rJ[k];
    a11[k]=(dxx*dxx+dxy*dxy)*rJ[k];
    const float pr = nC[3*k+2]*rJ[k];
    pqx[k]=pr*dxx; pqy[k]=pr*dxy;
  }
  float Vc[2],Voc[2],a22c[2];
  #pragma unroll
  for (int i=0;i<2;i++){
    const int m=1+i;
    Vc[i] =(nC[3*m]*dex_[m] + nC[3*m+1]*dey_[m])*rJ[m];
    Voc[i]=(qC[3*m]*dex_[m] + qC[3*m+1]*dey_[m])*rJ[m];
    a22c[i]=(dex_[m]*dex_[m]+dey_[m]*dey_[m])*rJ[m];
  }
  // south / north rows (2 nodes each, patch cols 1,2)
  float VnS[2],VoS[2],a22S[2],pexS[2],peyS[2];
  float VnN[2],VoN[2],a22N[2],pexN[2],peyN[2];
  #pragma unroll
  for (int i=0;i<2;i++){
    const int m=1+i;
    {
      const float de=ms[5*i+2], dn=ms[5*i+3], r=1.f/ms[5*i+4];
      VnS[i]=(nS[3*m]*de + nS[3*m+1]*dn)*r;
      VoS[i]=(qS[3*i]*de + qS[3*i+1]*dn)*r;
      a22S[i]=(de*de+dn*dn)*r;
      const float pr=nS[3*m+2]*r;
      pexS[i]=pr*de; peyS[i]=pr*dn;
    }
    {
      const float de=mn[5*i+2], dn=mn[5*i+3], r=1.f/mn[5*i+4];
      VnN[i]=(nN[3*m]*de + nN[3*m+1]*dn)*r;
      VoN[i]=(qN[3*i]*de + qN[3*i+1]*dn)*r;
      a22N[i]=(de*de+dn*dn)*r;
      const float pr=nN[3*m+2]*r;
      pexN[i]=pr*de; peyN[i]=pr*dn;
    }
  }

  const int o0 = jo*NXC + x0;
  float Lo[2],Mu[2],Mv[2],Vu[2],Vv[2],Vp[2];
  #pragma unroll
  for (int i=0;i<2;i++){
    const int m=1+i;
    const float Ufl =0.5f*(Un[m-1]+Un[m]), Ufr =0.5f*(Un[m]+Un[m+1]);
    const float Uflo=0.5f*(Uo[m-1]+Uo[m]), Ufro=0.5f*(Uo[m]+Uo[m+1]);
    const float Vfd =0.5f*(VnS[i]+Vc[i]),  Vfu =0.5f*(Vc[i]+VnN[i]);
    const float Vfdo=0.5f*(VoS[i]+Voc[i]), Vfuo=0.5f*(Voc[i]+VoN[i]);

    Lo[i] = (Ufr - Ufl + Vfu - Vfd) * cc;

    const float u_c=nC[3*m],   v_c=nC[3*m+1];
    const float uW =nC[3*m-3], vW =nC[3*m-2];
    const float uE =nC[3*m+3], vE =nC[3*m+4];
    const float uS =nS[3*m],   vS =nS[3*m+1];
    const float uN =nN[3*m],   vN =nN[3*m+1];

    const float cnu = 0.5f*(u_c+uE)*Ufr - 0.5f*(uW+u_c)*Ufl
                    + 0.5f*(u_c+uN)*Vfu - 0.5f*(uS+u_c)*Vfd;
    const float cnv = 0.5f*(v_c+vE)*Ufr - 0.5f*(vW+v_c)*Ufl
                    + 0.5f*(v_c+vN)*Vfu - 0.5f*(vS+v_c)*Vfd;

    const float uoc=qC[3*m],   voc=qC[3*m+1];
    const float uoW=qC[3*m-3], voW=qC[3*m-2];
    const float uoE=qC[3*m+3], voE=qC[3*m+4];
    const float uoS=qS[3*i],   voS=qS[3*i+1];
    const float uoN=qN[3*i],   voN=qN[3*i+1];

    const float cou = 0.5f*(uoc+uoE)*Ufro - 0.5f*(uoW+uoc)*Uflo
                    + 0.5f*(uoc+uoN)*Vfuo - 0.5f*(uoS+uoc)*Vfdo;
    const float cov = 0.5f*(voc+voE)*Ufro - 0.5f*(voW+voc)*Uflo
                    + 0.5f*(voc+voN)*Vfuo - 0.5f*(voS+voc)*Vfdo;

    const float convu = relax*cou + (1.f-relax)*cnu;
    const float convv = relax*cov + (1.f-relax)*cnv;

    const float du = 0.5f*(a11[m]+a11[m+1])*(uE-u_c) - 0.5f*(a11[m-1]+a11[m])*(u_c-uW)
                   + 0.5f*(a22c[i]+a22N[i])*(uN-u_c) - 0.5f*(a22S[i]+a22c[i])*(u_c-uS);
    const float dv = 0.5f*(a11[m]+a11[m+1])*(vE-v_c) - 0.5f*(a11[m-1]+a11[m])*(v_c-vW)
                   + 0.5f*(a22c[i]+a22N[i])*(vN-v_c) - 0.5f*(a22S[i]+a22c[i])*(v_c-vS);

    const float gPx = 0.5f*(pqx[m+1]-pqx[m-1]) + 0.5f*(pexN[i]-pexS[i]);
    const float gPy = 0.5f*(peyN[i]-peyS[i]) + 0.5f*(pqy[m+1]-pqy[m-1]);

    const float unst_u = (u_c - uoc)*rdt*rJ[m];
    const float unst_v = (v_c - voc)*rdt*rJ[m];

    Mu[i] = uc*unst_u + convc*convu + pc*gPx - dc*du;
    Mv[i] = uc*unst_v + convc*convv + pc*gPy - dc*dv;

    Vu[i] = (nS[3*m-3]+2.f*nS[3*m]+nS[3*m+3]
       +2.f*(nC[3*m-3]+2.f*nC[3*m]+nC[3*m+3])
           + nN[3*m-3]+2.f*nN[3*m]+nN[3*m+3])*0.0625f;
    Vv[i] = (nS[3*m-2]+2.f*nS[3*m+1]+nS[3*m+4]
       +2.f*(nC[3*m-2]+2.f*nC[3*m+1]+nC[3*m+4])
           + nN[3*m-2]+2.f*nN[3*m+1]+nN[3*m+4])*0.0625f;
    Vp[i] = (nS[3*m-1]+2.f*nS[3*m+2]+nS[3*m+5]
       +2.f*(nC[3*m-1]+2.f*nC[3*m+2]+nC[3*m+5])
           + nN[3*m-1]+2.f*nN[3*m+2]+nN[3*m+5])*0.0625f;
  }

  // stores: 2 contiguous floats per array, 6 contiguous for vis
  out[o0]          = Lo[0]; out[o0+1]        = Lo[1];
  out[NN+o0]       = Mu[0]; out[NN+o0+1]     = Mu[1];
  out[2*NN+o0]     = Mv[0]; out[2*NN+o0+1]   = Mv[1];
  const int vb = 3*NN + 3*o0;
  out[vb]   = Vu[0]; out[vb+1] = Vv[0]; out[vb+2] = Vp[0];
  out[vb+3] = Vu[1]; out[vb+4] = Vv[1]; out[vb+5] = Vp[1];
}

extern "C" void kernel_launch(void* const* d_in, const int* in_sizes, int n_in,
                              void* d_out, int out_size, void* d_ws, size_t ws_size,
                              hipStream_t stream) {
  const float* uvp = (const float*)d_in[0];   // original_uv
  const float* uvo = (const float*)d_in[1];   // uv_old
  const float* ndy = (const float*)d_in[2];   // node_y
  const float* ebm = (const float*)d_in[4];   // extended_block_metrics
  const float* dtg = (const float*)d_in[5];   // dt_graph
  const float* th  = (const float*)d_in[6];   // pde_theta
  const float* rl  = (const float*)d_in[7];   // relaxtion
  float* out = (float*)d_out;

  // one block per grid row: 1024 blocks x 512 threads (2 outputs/thread)
  fd_kernel<<<dim3(NXC), dim3(512), 0, stream>>>(uvp, uvo, ndy, ebm, dtg, th, rl, out);
}

// Round 4
// 181.977 us; speedup vs baseline: 1.0842x; 1.0842x over previous
//
#include <hip/hip_runtime.h>

// FD_discretizer on fixed 1024x1024 grid, Ex=Ey=1026 extended grid.
// Round 4: single launch, two block roles.
//  - blocks 0..11   : boundary frame (6136 nodes) via verified slow path
//  - blocks 12..1035: pure fast path, tile = 8 rows x 128 cols, 2 cols/thread.
//    ct = (bid-12)&7 gives each XCD one full-height column strip (bid%8 = XCD)
//    so vertically-shared rows stay in one XCD's L2.

#define NXC 1024               // NX == NY
#define EXC 1026               // Ex == Ey
#define NN  (NXC*NXC)

enum { T_NORMAL=0, T_INFLOW=4, T_OUTFLOW=5, T_WALL=6, T_PRESS=7 };

struct V3 { float u,v,p; };

__device__ __forceinline__ int ntype(int io,int jo){
  if (io==NXC-1) return T_OUTFLOW;
  if (io==0)     return T_INFLOW;
  if (jo==0 || jo==NXC-1) return T_WALL;
  return T_NORMAL;
}

// BC-enforced extended field value at extended coords (je,ie) in [0,1025]^2.
template<bool NEWF>
__device__ __forceinline__ V3 ext_at(int je,int ie,
    const float* __restrict__ uvp,
    const float* __restrict__ node_y)
{
  V3 r;
  const bool bl=(ie==0), br=(ie==EXC-1), bb=(je==0), bt=(je==EXC-1);
  const bool onx = bl||br, ony = bb||bt;
  const bool ghost = (onx && !ony) || (ony && !onx);   // ring minus corners
  if (!ghost){
    int io = ie-1; io = io<0?0:(io>NXC-1?NXC-1:io);
    int jo = je-1; jo = jo<0?0:(jo>NXC-1?NXC-1:jo);
    int m3 = 3*(jo*NXC+io);
    r.u = uvp[m3]; r.v = uvp[m3+1]; r.p = uvp[m3+2];
    if (NEWF && je==EXC/2 && ie==EXC/2) r.p = 0.f;     // PRESS_POINT
    return r;
  }
  int dje=0, die=0, gt;
  if (bl)      { die= 1; gt=T_INFLOW;  }
  else if (br) { die=-1; gt=T_OUTFLOW; }
  else if (bb) { dje= 1; gt=T_WALL;    }
  else         { dje=-1; gt=T_WALL;    }
  int io1 = ie+die-1, jo1 = je+dje-1;
  int m1 = 3*(jo1*NXC+io1);
  int m2 = 3*((jo1+dje)*NXC + (io1+die));
  float u2=uvp[m2], v2=uvp[m2+1], p2=uvp[m2+2];
  int nt1 = ntype(io1,jo1);
  if (gt==T_OUTFLOW){
    float p1 = (nt1==T_OUTFLOW) ? 0.f : uvp[m1+2];
    r.u=u2; r.v=v2; r.p = 2.f*p1 - p2;
  } else {
    float du,dv;
    if (nt1==T_INFLOW || nt1==T_WALL){ du=node_y[m1]; dv=node_y[m1+1]; }
    else                             { du=uvp[m1];    dv=uvp[m1+1];    }
    r.u = 2.f*du - u2; r.v = 2.f*dv - v2; r.p = p2;
  }
  return r;
}

// full slow-path computation for one output node (round-2-verified)
__device__ void process_slow(int io,int jo,
    const float* __restrict__ uvp, const float* __restrict__ uvo,
    const float* __restrict__ ndy, const float* __restrict__ ebm,
    float dt,float uc,float cc,float convc,float pc,float dc,float relax,
    float* __restrict__ out)
{
  const int o = jo*NXC + io;
  const int ie0 = io+1, je0 = jo+1;
  V3 C  = ext_at<true >(je0,  ie0,  uvp, ndy);
  V3 W  = ext_at<true >(je0,  ie0-1,uvp, ndy);
  V3 E  = ext_at<true >(je0,  ie0+1,uvp, ndy);
  V3 S  = ext_at<true >(je0-1,ie0,  uvp, ndy);
  V3 Nn = ext_at<true >(je0+1,ie0,  uvp, ndy);
  V3 SW = ext_at<true >(je0-1,ie0-1,uvp, ndy);
  V3 SE = ext_at<true >(je0-1,ie0+1,uvp, ndy);
  V3 NW = ext_at<true >(je0+1,ie0-1,uvp, ndy);
  V3 NE = ext_at<true >(je0+1,ie0+1,uvp, ndy);
  V3 Co = ext_at<false>(je0,  ie0,  uvo, ndy);
  V3 Wo = ext_at<false>(je0,  ie0-1,uvo, ndy);
  V3 Eo = ext_at<false>(je0,  ie0+1,uvo, ndy);
  V3 So = ext_at<false>(je0-1,ie0,  uvo, ndy);
  V3 No = ext_at<false>(je0+1,ie0,  uvo, ndy);

  const int eC = je0*EXC+ie0;
  const int eW = eC-1, eE = eC+1, eS = eC-EXC, eN = eC+EXC;
  float dxxC=ebm[5*eC+0], dxyC=ebm[5*eC+1], dexC=ebm[5*eC+2],
        deyC=ebm[5*eC+3], JmC=ebm[5*eC+4];
  float dxxW=ebm[5*eW+0], dxyW=ebm[5*eW+1], JmW=ebm[5*eW+4];
  float dxxE=ebm[5*eE+0], dxyE=ebm[5*eE+1], JmE=ebm[5*eE+4];
  float dexS=ebm[5*eS+2], deyS=ebm[5*eS+3], JmS=ebm[5*eS+4];
  float dexN=ebm[5*eN+2], deyN=ebm[5*eN+3], JmN=ebm[5*eN+4];
  const float rC=1.f/JmC, rW=1.f/JmW, rE=1.f/JmE, rS=1.f/JmS, rN=1.f/JmN;

  float UC=(C.u*dxxC + C.v*dxyC)*rC, UW=(W.u*dxxW + W.v*dxyW)*rW, UE=(E.u*dxxE + E.v*dxyE)*rE;
  float VC=(C.u*dexC + C.v*deyC)*rC, VS=(S.u*dexS + S.v*deyS)*rS, VN=(Nn.u*dexN + Nn.v*deyN)*rN;
  float UCo=(Co.u*dxxC + Co.v*dxyC)*rC, UWo=(Wo.u*dxxW + Wo.v*dxyW)*rW, UEo=(Eo.u*dxxE + Eo.v*dxyE)*rE;
  float VCo=(Co.u*dexC + Co.v*deyC)*rC, VSo=(So.u*dexS + So.v*deyS)*rS, VNo=(No.u*dexN + No.v*deyN)*rN;

  float Ufl =0.5f*(UW +UC ), Ufr =0.5f*(UC +UE );
  float Vfd =0.5f*(VS +VC ), Vfu =0.5f*(VC +VN );
  float Uflo=0.5f*(UWo+UCo), Ufro=0.5f*(UCo+UEo);
  float Vfdo=0.5f*(VSo+VCo), Vfuo=0.5f*(VCo+VNo);

  const float loss = (Ufr - Ufl + Vfu - Vfd) * cc;

  float cnu = 0.5f*(C.u+E.u)*Ufr - 0.5f*(W.u+C.u)*Ufl + 0.5f*(C.u+Nn.u)*Vfu - 0.5f*(S.u+C.u)*Vfd;
  float cnv = 0.5f*(C.v+E.v)*Ufr - 0.5f*(W.v+C.v)*Ufl + 0.5f*(C.v+Nn.v)*Vfu - 0.5f*(S.v+C.v)*Vfd;
  float cou = 0.5f*(Co.u+Eo.u)*Ufro - 0.5f*(Wo.u+Co.u)*Uflo + 0.5f*(Co.u+No.u)*Vfuo - 0.5f*(So.u+Co.u)*Vfdo;
  float cov = 0.5f*(Co.v+Eo.v)*Ufro - 0.5f*(Wo.v+Co.v)*Uflo + 0.5f*(Co.v+No.v)*Vfuo - 0.5f*(So.v+Co.v)*Vfdo;
  const float convu = relax*cou + (1.f-relax)*cnu;
  const float convv = relax*cov + (1.f-relax)*cnv;

  float a11C=(dxxC*dxxC+dxyC*dxyC)*rC, a11W=(dxxW*dxxW+dxyW*dxyW)*rW, a11E=(dxxE*dxxE+dxyE*dxyE)*rE;
  float a22C=(dexC*dexC+deyC*deyC)*rC, a22S=(dexS*dexS+deyS*deyS)*rS, a22N=(dexN*dexN+deyN*deyN)*rN;
  float du = 0.5f*(a11C+a11E)*(E.u -C.u) - 0.5f*(a11W+a11C)*(C.u-W.u)
           + 0.5f*(a22C+a22N)*(Nn.u-C.u) - 0.5f*(a22S+a22C)*(C.u-S.u);
  float dv = 0.5f*(a11C+a11E)*(E.v -C.v) - 0.5f*(a11W+a11C)*(C.v-W.v)
           + 0.5f*(a22C+a22N)*(Nn.v-C.v) - 0.5f*(a22S+a22C)*(C.v-S.v);

  float pqW=W.p*rW, pqE=E.p*rE, pqS=S.p*rS, pqN=Nn.p*rN;
  const float gPx = 0.5f*(pqE*dxxE - pqW*dxxW) + 0.5f*(pqN*dexN - pqS*dexS);
  const float gPy = 0.5f*(pqN*deyN - pqS*deyS) + 0.5f*(pqE*dxyE - pqW*dxyW);

  const float rdt = 1.f/dt;
  const float unst_u = (C.u - Co.u)*rdt*rC;
  const float unst_v = (C.v - Co.v)*rdt*rC;

  const float momu = uc*unst_u + convc*convu + pc*gPx - dc*du;
  const float momv = uc*unst_v + convc*convv + pc*gPy - dc*dv;

  const float visu = (SW.u+SE.u+NW.u+NE.u + 2.f*(S.u+W.u+E.u+Nn.u) + 4.f*C.u)*0.0625f;
  const float visv = (SW.v+SE.v+NW.v+NE.v + 2.f*(S.v+W.v+E.v+Nn.v) + 4.f*C.v)*0.0625f;
  const float visp = (SW.p+SE.p+NW.p+NE.p + 2.f*(S.p+W.p+E.p+Nn.p) + 4.f*C.p)*0.0625f;

  out[o]        = loss;
  out[NN + o]   = momu;
  out[2*NN + o] = momv;
  const int vb = 3*NN + 3*o;
  out[vb]   = visu;
  out[vb+1] = visv;
  out[vb+2] = visp;
}

#define NEDGE_BLK 12

extern "C" __global__ void __launch_bounds__(512)
fd_kernel(const float* __restrict__ uvp,     // original_uv  n x 3
          const float* __restrict__ uvo,     // uv_old       n x 3
          const float* __restrict__ ndy,     // node_y       n x 3
          const float* __restrict__ ebm,     // ext metrics  n_ext x 5
          const float* __restrict__ dtg,     // dt           1
          const float* __restrict__ th,      // pde_theta    5
          const float* __restrict__ rl,      // relaxation   1
          float* __restrict__ out)
{
  const int bid = blockIdx.x;
  const int tid = threadIdx.x;

  // scalars (uniform -> scalar loads)
  const float dt   = dtg[0];
  const float uc   = th[0], cc = th[1], convc = th[2], pc = th[3], dc = th[4];
  const float relax= rl[0];
  const float rdt  = 1.f/dt;

  if (bid < NEDGE_BLK){
    // ---- boundary frame: jo in {0,1023} all io, plus io in {0,1,1022,1023}
    // for jo in [1,1022]. 6136 nodes, 1 node/thread.
    const int t = bid*512 + tid;
    if (t >= 6136) return;
    int io, jo;
    if (t < 2048){ jo = (t < 1024) ? 0 : 1023; io = t & 1023; }
    else { int u = t - 2048; jo = 1 + (u >> 2); int c = u & 3; io = (c < 2) ? c : 1020 + c; }
    process_slow(io, jo, uvp,uvo,ndy,ebm, dt,uc,cc,convc,pc,dc,relax, out);
    return;
  }

  // ---------------- fast path: tile = 8 rows x 128 cols, 2 cols/thread -----
  const int b  = bid - NEDGE_BLK;
  const int ct = b & 7, rt = b >> 3;         // ct -> fixed XCD column strip
  const int tx = tid & 63, ty = tid >> 6;
  const int x0 = 2 + ct*128 + 2*tx;          // output cols x0, x0+1
  const int jo = 1 + rt*8 + ty;              // output row
  if (x0 > 1020 || jo > 1022) return;

  // patch cols c=0..3 <-> interior cols x0-1+c <-> ext cols x0+c
  const int rm=jo-1, rc=jo, rp=jo+1;

  float nS[12], nC[12], nN[12];              // new field, 3 rows x 4 nodes x (u,v,p)
  {
    const float* a = uvp + 3*(rm*NXC + x0-1);
    const float* b2 = uvp + 3*(rc*NXC + x0-1);
    const float* c = uvp + 3*(rp*NXC + x0-1);
    #pragma unroll
    for (int k=0;k<12;k++){ nS[k]=a[k]; nC[k]=b2[k]; nN[k]=c[k]; }
  }
  float qS[6], qC[12], qN[6];                // old field
  {
    const float* a = uvo + 3*(rm*NXC + x0);
    const float* b2 = uvo + 3*(rc*NXC + x0-1);
    const float* c = uvo + 3*(rp*NXC + x0);
    #pragma unroll
    for (int k=0;k<6;k++){ qS[k]=a[k]; qN[k]=c[k]; }
    #pragma unroll
    for (int k=0;k<12;k++){ qC[k]=b2[k]; }
  }
  float mc[20], ms[10], mn[10];              // metrics: center 4 nodes, N/S 2 nodes
  {
    const float* a = ebm + 5*((jo  )*EXC + x0+1);
    const float* b2 = ebm + 5*((jo+1)*EXC + x0);
    const float* c = ebm + 5*((jo+2)*EXC + x0+1);
    #pragma unroll
    for (int k=0;k<10;k++){ ms[k]=a[k]; mn[k]=c[k]; }
    #pragma unroll
    for (int k=0;k<20;k++){ mc[k]=b2[k]; }
  }

  // PRESS_POINT: interior node (512,512) p=0 in the NEW field only
  {
    const int c = 513 - x0;                  // patch col of interior col 512
    if ((unsigned)c < 4u){
      if (rm==512) nS[3*c+2]=0.f;
      if (rc==512) nC[3*c+2]=0.f;
      if (rp==512) nN[3*c+2]=0.f;
    }
  }

  // center-row per-column quantities
  float Un[4],Uo[4],a11[4],pqx[4],pqy[4],rJ[4],dex_[4],dey_[4];
  #pragma unroll
  for (int k=0;k<4;k++){
    const float dxx=mc[5*k], dxy=mc[5*k+1];
    dex_[k]=mc[5*k+2]; dey_[k]=mc[5*k+3];
    rJ[k]=1.f/mc[5*k+4];
    Un[k]=(nC[3*k]*dxx + nC[3*k+1]*dxy)*rJ[k];
    Uo[k]=(qC[3*k]*dxx + qC[3*k+1]*dxy)*rJ[k];
    a11[k]=(dxx*dxx+dxy*dxy)*rJ[k];
    const float pr = nC[3*k+2]*rJ[k];
    pqx[k]=pr*dxx; pqy[k]=pr*dxy;
  }
  float Vc[2],Voc[2],a22c[2];
  #pragma unroll
  for (int i=0;i<2;i++){
    const int m=1+i;
    Vc[i] =(nC[3*m]*dex_[m] + nC[3*m+1]*dey_[m])*rJ[m];
    Voc[i]=(qC[3*m]*dex_[m] + qC[3*m+1]*dey_[m])*rJ[m];
    a22c[i]=(dex_[m]*dex_[m]+dey_[m]*dey_[m])*rJ[m];
  }
  // south / north rows (2 nodes each, patch cols 1,2)
  float VnS[2],VoS[2],a22S[2],pexS[2],peyS[2];
  float VnN[2],VoN[2],a22N[2],pexN[2],peyN[2];
  #pragma unroll
  for (int i=0;i<2;i++){
    const int m=1+i;
    {
      const float de=ms[5*i+2], dn=ms[5*i+3], r=1.f/ms[5*i+4];
      VnS[i]=(nS[3*m]*de + nS[3*m+1]*dn)*r;
      VoS[i]=(qS[3*i]*de + qS[3*i+1]*dn)*r;
      a22S[i]=(de*de+dn*dn)*r;
      const float pr=nS[3*m+2]*r;
      pexS[i]=pr*de; peyS[i]=pr*dn;
    }
    {
      const float de=mn[5*i+2], dn=mn[5*i+3], r=1.f/mn[5*i+4];
      VnN[i]=(nN[3*m]*de + nN[3*m+1]*dn)*r;
      VoN[i]=(qN[3*i]*de + qN[3*i+1]*dn)*r;
      a22N[i]=(de*de+dn*dn)*r;
      const float pr=nN[3*m+2]*r;
      pexN[i]=pr*de; peyN[i]=pr*dn;
    }
  }

  const int o0 = jo*NXC + x0;
  float Lo[2],Mu[2],Mv[2],Vu[2],Vv[2],Vp[2];
  #pragma unroll
  for (int i=0;i<2;i++){
    const int m=1+i;
    const float Ufl =0.5f*(Un[m-1]+Un[m]), Ufr =0.5f*(Un[m]+Un[m+1]);
    const float Uflo=0.5f*(Uo[m-1]+Uo[m]), Ufro=0.5f*(Uo[m]+Uo[m+1]);
    const float Vfd =0.5f*(VnS[i]+Vc[i]),  Vfu =0.5f*(Vc[i]+VnN[i]);
    const float Vfdo=0.5f*(VoS[i]+Voc[i]), Vfuo=0.5f*(Voc[i]+VoN[i]);

    Lo[i] = (Ufr - Ufl + Vfu - Vfd) * cc;

    const float u_c=nC[3*m],   v_c=nC[3*m+1];
    const float uW =nC[3*m-3], vW =nC[3*m-2];
    const float uE =nC[3*m+3], vE =nC[3*m+4];
    const float uS =nS[3*m],   vS =nS[3*m+1];
    const float uN =nN[3*m],   vN =nN[3*m+1];

    const float cnu = 0.5f*(u_c+uE)*Ufr - 0.5f*(uW+u_c)*Ufl
                    + 0.5f*(u_c+uN)*Vfu - 0.5f*(uS+u_c)*Vfd;
    const float cnv = 0.5f*(v_c+vE)*Ufr - 0.5f*(vW+v_c)*Ufl
                    + 0.5f*(v_c+vN)*Vfu - 0.5f*(vS+v_c)*Vfd;

    const float uoc=qC[3*m],   voc=qC[3*m+1];
    const float uoW=qC[3*m-3], voW=qC[3*m-2];
    const float uoE=qC[3*m+3], voE=qC[3*m+4];
    const float uoS=qS[3*i],   voS=qS[3*i+1];
    const float uoN=qN[3*i],   voN=qN[3*i+1];

    const float cou = 0.5f*(uoc+uoE)*Ufro - 0.5f*(uoW+uoc)*Uflo
                    + 0.5f*(uoc+uoN)*Vfuo - 0.5f*(uoS+uoc)*Vfdo;
    const float cov = 0.5f*(voc+voE)*Ufro - 0.5f*(voW+voc)*Uflo
                    + 0.5f*(voc+voN)*Vfuo - 0.5f*(voS+voc)*Vfdo;

    const float convu = relax*cou + (1.f-relax)*cnu;
    const float convv = relax*cov + (1.f-relax)*cnv;

    const float du = 0.5f*(a11[m]+a11[m+1])*(uE-u_c) - 0.5f*(a11[m-1]+a11[m])*(u_c-uW)
                   + 0.5f*(a22c[i]+a22N[i])*(uN-u_c) - 0.5f*(a22S[i]+a22c[i])*(u_c-uS);
    const float dv = 0.5f*(a11[m]+a11[m+1])*(vE-v_c) - 0.5f*(a11[m-1]+a11[m])*(v_c-vW)
                   + 0.5f*(a22c[i]+a22N[i])*(vN-v_c) - 0.5f*(a22S[i]+a22c[i])*(v_c-vS);

    const float gPx = 0.5f*(pqx[m+1]-pqx[m-1]) + 0.5f*(pexN[i]-pexS[i]);
    const float gPy = 0.5f*(peyN[i]-peyS[i]) + 0.5f*(pqy[m+1]-pqy[m-1]);

    const float unst_u = (u_c - uoc)*rdt*rJ[m];
    const float unst_v = (v_c - voc)*rdt*rJ[m];

    Mu[i] = uc*unst_u + convc*convu + pc*gPx - dc*du;
    Mv[i] = uc*unst_v + convc*convv + pc*gPy - dc*dv;

    Vu[i] = (nS[3*m-3]+2.f*nS[3*m]+nS[3*m+3]
       +2.f*(nC[3*m-3]+2.f*nC[3*m]+nC[3*m+3])
           + nN[3*m-3]+2.f*nN[3*m]+nN[3*m+3])*0.0625f;
    Vv[i] = (nS[3*m-2]+2.f*nS[3*m+1]+nS[3*m+4]
       +2.f*(nC[3*m-2]+2.f*nC[3*m+1]+nC[3*m+4])
           + nN[3*m-2]+2.f*nN[3*m+1]+nN[3*m+4])*0.0625f;
    Vp[i] = (nS[3*m-1]+2.f*nS[3*m+2]+nS[3*m+5]
       +2.f*(nC[3*m-1]+2.f*nC[3*m+2]+nC[3*m+5])
           + nN[3*m-1]+2.f*nN[3*m+2]+nN[3*m+5])*0.0625f;
  }

  // stores: 2 contiguous floats per array, 6 contiguous for vis
  out[o0]          = Lo[0]; out[o0+1]        = Lo[1];
  out[NN+o0]       = Mu[0]; out[NN+o0+1]     = Mu[1];
  out[2*NN+o0]     = Mv[0]; out[2*NN+o0+1]   = Mv[1];
  const int vb = 3*NN + 3*o0;
  out[vb]   = Vu[0]; out[vb+1] = Vv[0]; out[vb+2] = Vp[0];
  out[vb+3] = Vu[1]; out[vb+4] = Vv[1]; out[vb+5] = Vp[1];
}

extern "C" void kernel_launch(void* const* d_in, const int* in_sizes, int n_in,
                              void* d_out, int out_size, void* d_ws, size_t ws_size,
                              hipStream_t stream) {
  const float* uvp = (const float*)d_in[0];   // original_uv
  const float* uvo = (const float*)d_in[1];   // uv_old
  const float* ndy = (const float*)d_in[2];   // node_y
  const float* ebm = (const float*)d_in[4];   // extended_block_metrics
  const float* dtg = (const float*)d_in[5];   // dt_graph
  const float* th  = (const float*)d_in[6];   // pde_theta
  const float* rl  = (const float*)d_in[7];   // relaxtion
  float* out = (float*)d_out;

  // 12 edge blocks (first, so they overlap main work) + 8x128 fast tiles
  fd_kernel<<<dim3(NEDGE_BLK + 1024), dim3(512), 0, stream>>>(uvp, uvo, ndy, ebm, dtg, th, rl, out);
}